// Round 7
// baseline (6712.599 us; speedup 1.0000x reference)
//
#include <hip/hip_runtime.h>
#include <cstdint>
#include <cstddef>

#define B_ 64
#define S_ 512
#define I_ 256
#define H_ 512
#define E_ 512

typedef __attribute__((ext_vector_type(8))) short bf16x8;
typedef __attribute__((ext_vector_type(4))) float f32x4;

__device__ __forceinline__ unsigned short f2b(float x) {
    uint32_t u = __builtin_bit_cast(uint32_t, x);
    uint32_t r = u + 0x7fffu + ((u >> 16) & 1u);
    return (unsigned short)(r >> 16);
}

// Compiler-only ordering for type-punned LDS repack (round-3 lesson:
// uint64_t does not TBAA-alias unsigned short; HW keeps DS ops in order).
__device__ __forceinline__ void lds_repack_fence() {
    __atomic_signal_fence(__ATOMIC_SEQ_CST);
    __builtin_amdgcn_wave_barrier();
}

// Compiler-only: keep relaxed data loads from being hoisted above the poll.
__device__ __forceinline__ void poll_fence() {
    __atomic_signal_fence(__ATOMIC_SEQ_CST);
}

__device__ __forceinline__ int flag_ld(const int* p) {
    return __hip_atomic_load(p, __ATOMIC_RELAXED, __HIP_MEMORY_SCOPE_AGENT);
}
__device__ __forceinline__ uint64_t st_ld(const uint64_t* p) {
    return __hip_atomic_load(p, __ATOMIC_RELAXED, __HIP_MEMORY_SCOPE_AGENT);
}
__device__ __forceinline__ void st_st(uint64_t* p, uint64_t v) {
    __hip_atomic_store(p, v, __ATOMIC_RELAXED, __HIP_MEMORY_SCOPE_AGENT);
}

// ---- convert the three 512x512 recurrent matrices to bf16 (row-major) ----
__global__ __launch_bounds__(256) void conv_bf16(const float* __restrict__ whh,
                                                 const float* __restrict__ wya,
                                                 const float* __restrict__ waa,
                                                 unsigned short* __restrict__ owhh,
                                                 unsigned short* __restrict__ owya,
                                                 unsigned short* __restrict__ owaa) {
    int i = blockIdx.x * 256 + threadIdx.x;
    owhh[i] = f2b(whh[i]);
    owya[i] = f2b(wya[i]);
    owaa[i] = f2b(waa[i]);
}

__global__ __launch_bounds__(256) void init_state(uint32_t* __restrict__ p, int n) {
    int i = blockIdx.x * 256 + threadIdx.x;
    if (i < n) p[i] = 0u;
}

// ---------------- xw GEMM (fp32, unchanged — verified) ----------------
__global__ __launch_bounds__(256) void xw_gemm(const float* __restrict__ x,
                                               const float* __restrict__ W_ih,
                                               const float* __restrict__ b_ih,
                                               const float* __restrict__ b_hh,
                                               float* __restrict__ xw) {
    __shared__ float As[16][65];
    __shared__ float Bs[16][65];
    const int tid = threadIdx.x;
    const int m0 = blockIdx.y * 64;
    const int n0 = blockIdx.x * 64;

    const int lr = tid >> 2;
    const int lk = (tid & 3) * 4;

    const int m = m0 + lr;
    const float* xrow = x + ((size_t)(m & 63) * S_ + (m >> 6)) * I_;
    const float* brow = W_ih + (size_t)(n0 + lr) * I_;

    const int tm = (tid >> 4) * 4;
    const int tn = (tid & 15) * 4;

    float acc[4][4] = {{0.f}};

    for (int kt = 0; kt < I_; kt += 16) {
        float4 av = *(const float4*)(xrow + kt + lk);
        float4 bv = *(const float4*)(brow + kt + lk);
        As[lk + 0][lr] = av.x; As[lk + 1][lr] = av.y;
        As[lk + 2][lr] = av.z; As[lk + 3][lr] = av.w;
        Bs[lk + 0][lr] = bv.x; Bs[lk + 1][lr] = bv.y;
        Bs[lk + 2][lr] = bv.z; Bs[lk + 3][lr] = bv.w;
        __syncthreads();
#pragma unroll
        for (int k = 0; k < 16; ++k) {
            float a0 = As[k][tm + 0], a1 = As[k][tm + 1], a2 = As[k][tm + 2], a3 = As[k][tm + 3];
            float c0 = Bs[k][tn + 0], c1 = Bs[k][tn + 1], c2 = Bs[k][tn + 2], c3 = Bs[k][tn + 3];
            acc[0][0] += a0 * c0; acc[0][1] += a0 * c1; acc[0][2] += a0 * c2; acc[0][3] += a0 * c3;
            acc[1][0] += a1 * c0; acc[1][1] += a1 * c1; acc[1][2] += a1 * c2; acc[1][3] += a1 * c3;
            acc[2][0] += a2 * c0; acc[2][1] += a2 * c1; acc[2][2] += a2 * c2; acc[2][3] += a2 * c3;
            acc[3][0] += a3 * c0; acc[3][1] += a3 * c1; acc[3][2] += a3 * c2; acc[3][3] += a3 * c3;
        }
        __syncthreads();
    }

#pragma unroll
    for (int i = 0; i < 4; ++i) {
        int row = m0 + tm + i;
#pragma unroll
        for (int j = 0; j < 4; ++j) {
            int n = n0 + tn + j;
            xw[(size_t)row * H_ + n] = acc[i][j] + b_ih[n] + b_hh[n];
        }
    }
}

// ---------------- wave-autonomous MFMA scan, RMW-free signaling ----------------
// 48 WGs x 256 threads, no __syncthreads and NO atomic RMWs in the loop.
// blocks 0..15  : h-WGs (4/group). Wave w owns 32 h-cols; widx = (bid&3)*4+w in [0,16).
// blocks 16..47 : a-WGs (8/group). Wave w owns 16 a-cols; widx = 16+(idx&7)*4+w in [16,48).
// flags[g][0..15] = h-wave step published; flags[g][16..47] = a-wave step.
// Publish: lane0 RELEASE store flags[g][widx]=t (release drains the wave's
// state stores; parallel line commits, no RMW serialization — round-6 lesson:
// 48 serialized fetch_adds/step cost ~3.5 us/step).
// Poll: one coalesced 64-lane flag load + per-lane target + __ballot.
//   h-wave step t: lanes0-15 hflag>=t-1 (h_{t-1} ready), lanes16-47 aflag>=t-8
//                  (h-ring depth-8 WAR guard: a-wave publishing t-8 has read h_{t-8}).
//   a-wave step t: lanes0-15 hflag>=t (h_t ready), lanes16-47 aflag>=t-1
//                  (a_{t-1} ready; also a-ring WAR: publishers of t-1 are done
//                  reading a_{t-2}, so slot (t&1) is safe to overwrite).
__global__ __launch_bounds__(256) void scan_mfma(const float* __restrict__ xw,
                                                 const unsigned short* __restrict__ Whh_b,
                                                 const unsigned short* __restrict__ Wya_b,
                                                 const unsigned short* __restrict__ Waa_b,
                                                 const float* __restrict__ b_ya,
                                                 const float* __restrict__ b_aa,
                                                 unsigned short* __restrict__ hring,  // 8*64*512 bf16
                                                 unsigned short* __restrict__ aring,  // 2*64*512 bf16
                                                 int* __restrict__ flg,               // 4 groups x 64 ints
                                                 float* __restrict__ out) {
    const int bid  = blockIdx.x;
    const int tid  = threadIdx.x;
    const int wave = tid >> 6;
    const int lane = tid & 63;
    const int l15  = lane & 15;
    const int quad = lane >> 4;

    __shared__ unsigned short wlds[4 * 2 * 16 * 64 * 8];  // 128 KB, per-wave partition
    __shared__ unsigned short pk[4][512];                  // per-wave repack staging

    uint64_t* hr64 = (uint64_t*)hring;
    uint64_t* ar64 = (uint64_t*)aring;

    if (bid < 16) {
        // ---------------- h-side ----------------
        const int g    = bid >> 2;
        const int b0   = g * 16;
        const int jw   = (bid & 3) * 128 + wave * 32;
        const int widx = (bid & 3) * 4 + wave;
        int*       fl_self = flg + g * 64 + widx;
        const int* fl_lane = flg + g * 64 + lane;
        const int  off = (lane < 16) ? 1 : (lane < 48 ? 8 : (1 << 30));

        // stage private Whh B-frags: B[k][j] = Whh[j][k], 16B/lane/frag
#pragma unroll
        for (int idx = 0; idx < 32; ++idx) {
            int s = idx >> 4, kb = idx & 15;
            const unsigned short* src = Whh_b + (size_t)(jw + s * 16 + l15) * H_ + kb * 32 + quad * 8;
            *(uint4*)&wlds[(((wave * 2 + s) * 16 + kb) * 64 + lane) * 8] = *(const uint4*)src;
        }
        lds_repack_fence();   // staging stores (uint4) vs loop reads (bf16x8): TBAA

        unsigned short* mypk = &pk[wave][0];
        const int prow = lane >> 2, pcg = lane & 3;

        for (int t = 1; t <= S_; ++t) {
            // xw prefetch: issued before the poll, consumed after MFMA
            float xwv[2][4];
#pragma unroll
            for (int s = 0; s < 2; ++s)
#pragma unroll
                for (int r = 0; r < 4; ++r)
                    xwv[s][r] = xw[((size_t)(t - 1) * B_ + b0 + quad * 4 + r) * H_ + jw + s * 16 + l15];

            for (;;) {   // single merged poll: h_{t-1} ready + ring WAR guard
                int f = flag_ld(fl_lane);
                if (__ballot(f >= t - off) == ~0ull) break;
            }
            poll_fence();

            const uint64_t* hsrc = hr64 + (size_t)((t - 1) & 7) * 8192 + (size_t)(b0 + l15) * 128 + quad * 2;
            union { uint64_t q[2]; bf16x8 v; } hf[16];
#pragma unroll
            for (int kb = 0; kb < 16; ++kb) {
                hf[kb].q[0] = st_ld(hsrc + kb * 8);
                hf[kb].q[1] = st_ld(hsrc + kb * 8 + 1);
            }
            f32x4 a0 = {0.f, 0.f, 0.f, 0.f}, a1 = {0.f, 0.f, 0.f, 0.f};
#pragma unroll
            for (int kb = 0; kb < 16; ++kb) {
                bf16x8 b0f = *(const bf16x8*)&wlds[(((wave * 2 + 0) * 16 + kb) * 64 + lane) * 8];
                bf16x8 b1f = *(const bf16x8*)&wlds[(((wave * 2 + 1) * 16 + kb) * 64 + lane) * 8];
                a0 = __builtin_amdgcn_mfma_f32_16x16x32_bf16(hf[kb].v, b0f, a0, 0, 0, 0);
                a1 = __builtin_amdgcn_mfma_f32_16x16x32_bf16(hf[kb].v, b1f, a1, 0, 0, 0);
            }
            // tanh + C-layout -> row-major repack (16 rows x 32 cols)
#pragma unroll
            for (int r = 0; r < 4; ++r) {
                mypk[(quad * 4 + r) * 32 + 0  + l15] = f2b(tanhf(xwv[0][r] + a0[r]));
                mypk[(quad * 4 + r) * 32 + 16 + l15] = f2b(tanhf(xwv[1][r] + a1[r]));
            }
            lds_repack_fence();
            {
                const uint64_t* pr = (const uint64_t*)mypk;   // [16][8] u64
                uint64_t v0 = pr[prow * 8 + pcg * 2];
                uint64_t v1 = pr[prow * 8 + pcg * 2 + 1];
                uint64_t* hdst = hr64 + (size_t)(t & 7) * 8192 + (size_t)(b0 + prow) * 128
                                 + (jw >> 2) + pcg * 2;
                st_st(hdst, v0);
                st_st(hdst + 1, v1);
            }
            if (lane == 0)   // RELEASE: drains this wave's stores, then one plain flag store
                __hip_atomic_store(fl_self, t, __ATOMIC_RELEASE, __HIP_MEMORY_SCOPE_AGENT);
        }
    } else {
        // ---------------- a-side ----------------
        const int idx  = bid - 16;
        const int g    = idx >> 3;
        const int b0   = g * 16;
        const int jw   = (idx & 7) * 64 + wave * 16;
        const int widx = 16 + (idx & 7) * 4 + wave;
        int*       fl_self = flg + g * 64 + widx;
        const int* fl_lane = flg + g * 64 + lane;
        const int  off = (lane < 16) ? 0 : (lane < 48 ? 1 : (1 << 30));

        // stage private Wya (s=0) and Waa (s=1) B-frags
#pragma unroll
        for (int m = 0; m < 2; ++m)
#pragma unroll
            for (int kb = 0; kb < 16; ++kb) {
                const unsigned short* wb = m ? Waa_b : Wya_b;
                const unsigned short* src = wb + (size_t)(jw + l15) * H_ + kb * 32 + quad * 8;
                *(uint4*)&wlds[(((wave * 2 + m) * 16 + kb) * 64 + lane) * 8] = *(const uint4*)src;
            }
        lds_repack_fence();
        const float bias_a = b_ya[jw + l15] + b_aa[jw + l15];

        unsigned short* mypk = &pk[wave][0];
        const int prow = lane >> 2, pcg = lane & 3;

        for (int t = 1; t <= S_; ++t) {
            for (;;) {   // single merged poll: h_t ready + a_{t-1} ready
                int f = flag_ld(fl_lane);
                if (__ballot(f >= t - off) == ~0ull) break;
            }
            poll_fence();

            // h_t and a_{t-1} loads issued together (parallel round trips)
            const uint64_t* hsrc = hr64 + (size_t)(t & 7) * 8192 + (size_t)(b0 + l15) * 128 + quad * 2;
            const uint64_t* asrc = ar64 + (size_t)((t - 1) & 1) * 8192 + (size_t)(b0 + l15) * 128 + quad * 2;
            union { uint64_t q[2]; bf16x8 v; } hf[16], af[16];
#pragma unroll
            for (int kb = 0; kb < 16; ++kb) {
                hf[kb].q[0] = st_ld(hsrc + kb * 8);
                hf[kb].q[1] = st_ld(hsrc + kb * 8 + 1);
                af[kb].q[0] = st_ld(asrc + kb * 8);
                af[kb].q[1] = st_ld(asrc + kb * 8 + 1);
            }
            f32x4 accy = {0.f, 0.f, 0.f, 0.f}, acca = {0.f, 0.f, 0.f, 0.f};
#pragma unroll
            for (int kb = 0; kb < 16; ++kb) {
                bf16x8 by = *(const bf16x8*)&wlds[(((wave * 2 + 0) * 16 + kb) * 64 + lane) * 8];
                bf16x8 ba = *(const bf16x8*)&wlds[(((wave * 2 + 1) * 16 + kb) * 64 + lane) * 8];
                accy = __builtin_amdgcn_mfma_f32_16x16x32_bf16(hf[kb].v, by, accy, 0, 0, 0);
                acca = __builtin_amdgcn_mfma_f32_16x16x32_bf16(af[kb].v, ba, acca, 0, 0, 0);
            }
            float av[4];
#pragma unroll
            for (int r = 0; r < 4; ++r)
                av[r] = tanhf(accy[r] + acca[r] + bias_a);

            if (t < S_) {
#pragma unroll
                for (int r = 0; r < 4; ++r)
                    mypk[(quad * 4 + r) * 16 + l15] = f2b(av[r]);
                lds_repack_fence();
                uint64_t v = ((const uint64_t*)mypk)[prow * 4 + pcg];
                uint64_t* adst = ar64 + (size_t)(t & 1) * 8192 + (size_t)(b0 + prow) * 128
                                 + (jw >> 2) + pcg;
                st_st(adst, v);
            } else {
#pragma unroll
                for (int r = 0; r < 4; ++r)
                    out[(size_t)(b0 + quad * 4 + r) * E_ + jw + l15] = av[r];
            }
            if (lane == 0)
                __hip_atomic_store(fl_self, t, __ATOMIC_RELEASE, __HIP_MEMORY_SCOPE_AGENT);
        }
    }
}

extern "C" void kernel_launch(void* const* d_in, const int* in_sizes, int n_in,
                              void* d_out, int out_size, void* d_ws, size_t ws_size,
                              hipStream_t stream) {
    const float* x    = (const float*)d_in[0];
    const float* W_ih = (const float*)d_in[1];
    const float* W_hh = (const float*)d_in[2];
    const float* b_ih = (const float*)d_in[3];
    const float* b_hh = (const float*)d_in[4];
    const float* W_ya = (const float*)d_in[5];
    const float* b_ya = (const float*)d_in[6];
    const float* W_aa = (const float*)d_in[7];
    const float* b_aa = (const float*)d_in[8];
    float* out = (float*)d_out;

    char* ws = (char*)d_ws;
    const size_t MB = 1024 * 1024, KB = 1024;
    float*          xw    = (float*)(ws);                              // 64 MB
    unsigned short* Whh_b = (unsigned short*)(ws + 64 * MB);           // 512 KB
    unsigned short* Wya_b = (unsigned short*)(ws + 64 * MB + 512 * KB);
    unsigned short* Waa_b = (unsigned short*)(ws + 65 * MB);           // 512 KB
    unsigned short* hring = (unsigned short*)(ws + 65 * MB + 512 * KB);// 512 KB (8 slots)
    unsigned short* aring = (unsigned short*)(ws + 66 * MB);           // 128 KB (2 slots)
    int*            flg   = (int*)(ws + 66 * MB + 128 * KB);           // 1 KB (4x64 ints)

    conv_bf16<<<(H_ * H_) / 256, 256, 0, stream>>>(W_hh, W_ya, W_aa, Whh_b, Wya_b, Waa_b);

    // zero hring (512 KB) + aring (128 KB) contiguous = 163840 u32, then flags
    init_state<<<640, 256, 0, stream>>>((uint32_t*)hring, 163840);
    init_state<<<1,   256, 0, stream>>>((uint32_t*)flg, 256);

    dim3 gg(H_ / 64, (S_ * B_) / 64);
    xw_gemm<<<gg, 256, 0, stream>>>(x, W_ih, b_ih, b_hh, xw);

    scan_mfma<<<48, 256, 0, stream>>>(xw, Whh_b, Wya_b, Waa_b, b_ya, b_aa,
                                      hring, aring, flg, out);
}

// Round 8
// 4981.977 us; speedup vs baseline: 1.3474x; 1.3474x over previous
//
#include <hip/hip_runtime.h>
#include <cstdint>
#include <cstddef>

#define B_ 64
#define S_ 512
#define I_ 256
#define H_ 512
#define E_ 512

typedef __attribute__((ext_vector_type(8))) short bf16x8;
typedef __attribute__((ext_vector_type(4))) float f32x4;

__device__ __forceinline__ unsigned short f2b(float x) {
    uint32_t u = __builtin_bit_cast(uint32_t, x);
    uint32_t r = u + 0x7fffu + ((u >> 16) & 1u);
    return (unsigned short)(r >> 16);
}

// Compiler-only ordering for type-punned LDS repack (round-3 lesson:
// uint64_t does not TBAA-alias unsigned short; HW keeps DS ops in order).
__device__ __forceinline__ void lds_repack_fence() {
    __atomic_signal_fence(__ATOMIC_SEQ_CST);
    __builtin_amdgcn_wave_barrier();
}

// Compiler-only: keep relaxed data loads from being hoisted above the poll.
__device__ __forceinline__ void poll_fence() {
    __atomic_signal_fence(__ATOMIC_SEQ_CST);
}

// Drain this wave's outstanding VMEM (store acks reach the coherence point)
// WITHOUT any release semantics. Round 6/7 lesson: agent-scope RELEASE on
// multi-XCD gfx9 emits buffer_wbl2 (L2 dirty writeback) per signal — 48 of
// those per step tracked the 6.5->10->12.6 us/step regressions. s_waitcnt 0
// is a pure wait: no cache maintenance.
__device__ __forceinline__ void full_drain() {
    __atomic_signal_fence(__ATOMIC_SEQ_CST);
    __builtin_amdgcn_s_waitcnt(0);
    __atomic_signal_fence(__ATOMIC_SEQ_CST);
}

__device__ __forceinline__ int flag_ld(const int* p) {
    return __hip_atomic_load(p, __ATOMIC_RELAXED, __HIP_MEMORY_SCOPE_AGENT);
}
__device__ __forceinline__ void flag_st(int* p, int v) {
    __hip_atomic_store(p, v, __ATOMIC_RELAXED, __HIP_MEMORY_SCOPE_AGENT);
}
__device__ __forceinline__ uint64_t st_ld(const uint64_t* p) {
    return __hip_atomic_load(p, __ATOMIC_RELAXED, __HIP_MEMORY_SCOPE_AGENT);
}
__device__ __forceinline__ void st_st(uint64_t* p, uint64_t v) {
    __hip_atomic_store(p, v, __ATOMIC_RELAXED, __HIP_MEMORY_SCOPE_AGENT);
}

// ---- convert the three 512x512 recurrent matrices to bf16 (row-major) ----
__global__ __launch_bounds__(256) void conv_bf16(const float* __restrict__ whh,
                                                 const float* __restrict__ wya,
                                                 const float* __restrict__ waa,
                                                 unsigned short* __restrict__ owhh,
                                                 unsigned short* __restrict__ owya,
                                                 unsigned short* __restrict__ owaa) {
    int i = blockIdx.x * 256 + threadIdx.x;
    owhh[i] = f2b(whh[i]);
    owya[i] = f2b(wya[i]);
    owaa[i] = f2b(waa[i]);
}

__global__ __launch_bounds__(256) void init_state(uint32_t* __restrict__ p, int n) {
    int i = blockIdx.x * 256 + threadIdx.x;
    if (i < n) p[i] = 0u;
}

// ---------------- xw GEMM (fp32, unchanged — verified) ----------------
__global__ __launch_bounds__(256) void xw_gemm(const float* __restrict__ x,
                                               const float* __restrict__ W_ih,
                                               const float* __restrict__ b_ih,
                                               const float* __restrict__ b_hh,
                                               float* __restrict__ xw) {
    __shared__ float As[16][65];
    __shared__ float Bs[16][65];
    const int tid = threadIdx.x;
    const int m0 = blockIdx.y * 64;
    const int n0 = blockIdx.x * 64;

    const int lr = tid >> 2;
    const int lk = (tid & 3) * 4;

    const int m = m0 + lr;
    const float* xrow = x + ((size_t)(m & 63) * S_ + (m >> 6)) * I_;
    const float* brow = W_ih + (size_t)(n0 + lr) * I_;

    const int tm = (tid >> 4) * 4;
    const int tn = (tid & 15) * 4;

    float acc[4][4] = {{0.f}};

    for (int kt = 0; kt < I_; kt += 16) {
        float4 av = *(const float4*)(xrow + kt + lk);
        float4 bv = *(const float4*)(brow + kt + lk);
        As[lk + 0][lr] = av.x; As[lk + 1][lr] = av.y;
        As[lk + 2][lr] = av.z; As[lk + 3][lr] = av.w;
        Bs[lk + 0][lr] = bv.x; Bs[lk + 1][lr] = bv.y;
        Bs[lk + 2][lr] = bv.z; Bs[lk + 3][lr] = bv.w;
        __syncthreads();
#pragma unroll
        for (int k = 0; k < 16; ++k) {
            float a0 = As[k][tm + 0], a1 = As[k][tm + 1], a2 = As[k][tm + 2], a3 = As[k][tm + 3];
            float c0 = Bs[k][tn + 0], c1 = Bs[k][tn + 1], c2 = Bs[k][tn + 2], c3 = Bs[k][tn + 3];
            acc[0][0] += a0 * c0; acc[0][1] += a0 * c1; acc[0][2] += a0 * c2; acc[0][3] += a0 * c3;
            acc[1][0] += a1 * c0; acc[1][1] += a1 * c1; acc[1][2] += a1 * c2; acc[1][3] += a1 * c3;
            acc[2][0] += a2 * c0; acc[2][1] += a2 * c1; acc[2][2] += a2 * c2; acc[2][3] += a2 * c3;
            acc[3][0] += a3 * c0; acc[3][1] += a3 * c1; acc[3][2] += a3 * c2; acc[3][3] += a3 * c3;
        }
        __syncthreads();
    }

#pragma unroll
    for (int i = 0; i < 4; ++i) {
        int row = m0 + tm + i;
#pragma unroll
        for (int j = 0; j < 4; ++j) {
            int n = n0 + tn + j;
            xw[(size_t)row * H_ + n] = acc[i][j] + b_ih[n] + b_hh[n];
        }
    }
}

// ---------------- wave-autonomous MFMA scan, release-free signaling ----------------
// 48 WGs x 256 threads; no __syncthreads, no RMWs, NO release/acquire in loop.
// blocks 0..15  : h-WGs (4/group g=bid>>2). Wave w owns 32 h-cols.
// blocks 16..47 : a-WGs (8/group g=(bid-16)>>3). Wave w owns 16 a-cols.
// Publish protocol per WG per step: each wave stores state (relaxed sc1),
// full_drain() (acks at coherence point), lane0 ds_add on a monotone LDS
// counter; the wave whose add returns 4t-1 stores the WG flag = t (relaxed).
// Transitivity: every wave's state is acked before its ds_add; the flag store
// is issued after observing all four adds -> state precedes flag at IC.
// Flags: flg[g*64 + 0..3] = h-WG flags; flg[g*64 + 4..11] = a-WG flags.
// Poll: one coalesced 12-word load + per-lane target + __ballot + s_sleep.
//   h-wave step t: hflag>=t-1 (h_{t-1} ready), aflag>=t-8 (h-ring depth-8 WAR).
//   a-wave step t: hflag>=t (h_t ready), aflag>=t-1 (a_{t-1} ready + a-ring WAR).
__global__ __launch_bounds__(256) void scan_mfma(const float* __restrict__ xw,
                                                 const unsigned short* __restrict__ Whh_b,
                                                 const unsigned short* __restrict__ Wya_b,
                                                 const unsigned short* __restrict__ Waa_b,
                                                 const float* __restrict__ b_ya,
                                                 const float* __restrict__ b_aa,
                                                 unsigned short* __restrict__ hring,  // 8*64*512 bf16
                                                 unsigned short* __restrict__ aring,  // 2*64*512 bf16
                                                 int* __restrict__ flg,               // 4 groups x 64 ints
                                                 float* __restrict__ out) {
    const int bid  = blockIdx.x;
    const int tid  = threadIdx.x;
    const int wave = tid >> 6;
    const int lane = tid & 63;
    const int l15  = lane & 15;
    const int quad = lane >> 4;

    __shared__ unsigned short wlds[4 * 2 * 16 * 64 * 8];  // 128 KB, per-wave partition
    __shared__ unsigned short pk[4][512];                  // per-wave repack staging
    __shared__ int sdone;                                  // monotone WG step counter

    if (tid == 0) sdone = 0;
    __syncthreads();   // once, before the loop

    uint64_t* hr64 = (uint64_t*)hring;
    uint64_t* ar64 = (uint64_t*)aring;

    if (bid < 16) {
        // ---------------- h-side ----------------
        const int g   = bid >> 2;
        const int b0  = g * 16;
        const int jw  = (bid & 3) * 128 + wave * 32;
        int*       fl_self = flg + g * 64 + (bid & 3);
        const int* fl_lane = flg + g * 64 + (lane < 12 ? lane : 0);
        const int  off = (lane < 4) ? 1 : (lane < 12 ? 8 : (1 << 30));

        // stage private Whh B-frags: B[k][j] = Whh[j][k], 16B/lane/frag
#pragma unroll
        for (int idx = 0; idx < 32; ++idx) {
            int s = idx >> 4, kb = idx & 15;
            const unsigned short* src = Whh_b + (size_t)(jw + s * 16 + l15) * H_ + kb * 32 + quad * 8;
            *(uint4*)&wlds[(((wave * 2 + s) * 16 + kb) * 64 + lane) * 8] = *(const uint4*)src;
        }
        lds_repack_fence();   // staging stores (uint4) vs loop reads (bf16x8): TBAA

        unsigned short* mypk = &pk[wave][0];
        const int prow = lane >> 2, pcg = lane & 3;

        for (int t = 1; t <= S_; ++t) {
            // xw prefetch: issued before the poll, consumed after MFMA
            float xwv[2][4];
#pragma unroll
            for (int s = 0; s < 2; ++s)
#pragma unroll
                for (int r = 0; r < 4; ++r)
                    xwv[s][r] = xw[((size_t)(t - 1) * B_ + b0 + quad * 4 + r) * H_ + jw + s * 16 + l15];

            for (;;) {   // merged poll: h_{t-1} ready + h-ring WAR guard
                int f = flag_ld(fl_lane);
                if (__ballot(f >= t - off) == ~0ull) break;
                __builtin_amdgcn_s_sleep(1);
            }
            poll_fence();

            const uint64_t* hsrc = hr64 + (size_t)((t - 1) & 7) * 8192 + (size_t)(b0 + l15) * 128 + quad * 2;
            union { uint64_t q[2]; bf16x8 v; } hf[16];
#pragma unroll
            for (int kb = 0; kb < 16; ++kb) {
                hf[kb].q[0] = st_ld(hsrc + kb * 8);
                hf[kb].q[1] = st_ld(hsrc + kb * 8 + 1);
            }
            f32x4 a0 = {0.f, 0.f, 0.f, 0.f}, a1 = {0.f, 0.f, 0.f, 0.f};
#pragma unroll
            for (int kb = 0; kb < 16; ++kb) {
                bf16x8 b0f = *(const bf16x8*)&wlds[(((wave * 2 + 0) * 16 + kb) * 64 + lane) * 8];
                bf16x8 b1f = *(const bf16x8*)&wlds[(((wave * 2 + 1) * 16 + kb) * 64 + lane) * 8];
                a0 = __builtin_amdgcn_mfma_f32_16x16x32_bf16(hf[kb].v, b0f, a0, 0, 0, 0);
                a1 = __builtin_amdgcn_mfma_f32_16x16x32_bf16(hf[kb].v, b1f, a1, 0, 0, 0);
            }
            // tanh + C-layout -> row-major repack (16 rows x 32 cols)
#pragma unroll
            for (int r = 0; r < 4; ++r) {
                mypk[(quad * 4 + r) * 32 + 0  + l15] = f2b(tanhf(xwv[0][r] + a0[r]));
                mypk[(quad * 4 + r) * 32 + 16 + l15] = f2b(tanhf(xwv[1][r] + a1[r]));
            }
            lds_repack_fence();
            {
                const uint64_t* pr = (const uint64_t*)mypk;   // [16][8] u64
                uint64_t v0 = pr[prow * 8 + pcg * 2];
                uint64_t v1 = pr[prow * 8 + pcg * 2 + 1];
                uint64_t* hdst = hr64 + (size_t)(t & 7) * 8192 + (size_t)(b0 + prow) * 128
                                 + (jw >> 2) + pcg * 2;
                st_st(hdst, v0);
                st_st(hdst + 1, v1);
            }
            full_drain();   // state acked at coherence point (no cache flush)
            if (lane == 0) {
                int old = __hip_atomic_fetch_add(&sdone, 1, __ATOMIC_RELAXED, __HIP_MEMORY_SCOPE_WORKGROUP);
                if (old == 4 * t - 1)
                    flag_st(fl_self, t);   // single relaxed WG flag store
            }
        }
    } else {
        // ---------------- a-side ----------------
        const int idx  = bid - 16;
        const int g    = idx >> 3;
        const int b0   = g * 16;
        const int jw   = (idx & 7) * 64 + wave * 16;
        int*       fl_self = flg + g * 64 + 4 + (idx & 7);
        const int* fl_lane = flg + g * 64 + (lane < 12 ? lane : 0);
        const int  off = (lane < 4) ? 0 : (lane < 12 ? 1 : (1 << 30));

        // stage private Wya (s=0) and Waa (s=1) B-frags
#pragma unroll
        for (int m = 0; m < 2; ++m)
#pragma unroll
            for (int kb = 0; kb < 16; ++kb) {
                const unsigned short* wb = m ? Waa_b : Wya_b;
                const unsigned short* src = wb + (size_t)(jw + l15) * H_ + kb * 32 + quad * 8;
                *(uint4*)&wlds[(((wave * 2 + m) * 16 + kb) * 64 + lane) * 8] = *(const uint4*)src;
            }
        lds_repack_fence();
        const float bias_a = b_ya[jw + l15] + b_aa[jw + l15];

        unsigned short* mypk = &pk[wave][0];
        const int prow = lane >> 2, pcg = lane & 3;

        for (int t = 1; t <= S_; ++t) {
            for (;;) {   // merged poll: h_t ready + a_{t-1} ready
                int f = flag_ld(fl_lane);
                if (__ballot(f >= t - off) == ~0ull) break;
                __builtin_amdgcn_s_sleep(1);
            }
            poll_fence();

            // h_t and a_{t-1} loads issued together (parallel round trips)
            const uint64_t* hsrc = hr64 + (size_t)(t & 7) * 8192 + (size_t)(b0 + l15) * 128 + quad * 2;
            const uint64_t* asrc = ar64 + (size_t)((t - 1) & 1) * 8192 + (size_t)(b0 + l15) * 128 + quad * 2;
            union { uint64_t q[2]; bf16x8 v; } hf[16], af[16];
#pragma unroll
            for (int kb = 0; kb < 16; ++kb) {
                hf[kb].q[0] = st_ld(hsrc + kb * 8);
                hf[kb].q[1] = st_ld(hsrc + kb * 8 + 1);
                af[kb].q[0] = st_ld(asrc + kb * 8);
                af[kb].q[1] = st_ld(asrc + kb * 8 + 1);
            }
            f32x4 accy = {0.f, 0.f, 0.f, 0.f}, acca = {0.f, 0.f, 0.f, 0.f};
#pragma unroll
            for (int kb = 0; kb < 16; ++kb) {
                bf16x8 by = *(const bf16x8*)&wlds[(((wave * 2 + 0) * 16 + kb) * 64 + lane) * 8];
                bf16x8 ba = *(const bf16x8*)&wlds[(((wave * 2 + 1) * 16 + kb) * 64 + lane) * 8];
                accy = __builtin_amdgcn_mfma_f32_16x16x32_bf16(hf[kb].v, by, accy, 0, 0, 0);
                acca = __builtin_amdgcn_mfma_f32_16x16x32_bf16(af[kb].v, ba, acca, 0, 0, 0);
            }
            float av[4];
#pragma unroll
            for (int r = 0; r < 4; ++r)
                av[r] = tanhf(accy[r] + acca[r] + bias_a);

            if (t < S_) {
#pragma unroll
                for (int r = 0; r < 4; ++r)
                    mypk[(quad * 4 + r) * 16 + l15] = f2b(av[r]);
                lds_repack_fence();
                uint64_t v = ((const uint64_t*)mypk)[prow * 4 + pcg];
                uint64_t* adst = ar64 + (size_t)(t & 1) * 8192 + (size_t)(b0 + prow) * 128
                                 + (jw >> 2) + pcg;
                st_st(adst, v);
            } else {
#pragma unroll
                for (int r = 0; r < 4; ++r)
                    out[(size_t)(b0 + quad * 4 + r) * E_ + jw + l15] = av[r];
            }
            full_drain();
            if (lane == 0) {
                int old = __hip_atomic_fetch_add(&sdone, 1, __ATOMIC_RELAXED, __HIP_MEMORY_SCOPE_WORKGROUP);
                if (old == 4 * t - 1)
                    flag_st(fl_self, t);
            }
        }
    }
}

extern "C" void kernel_launch(void* const* d_in, const int* in_sizes, int n_in,
                              void* d_out, int out_size, void* d_ws, size_t ws_size,
                              hipStream_t stream) {
    const float* x    = (const float*)d_in[0];
    const float* W_ih = (const float*)d_in[1];
    const float* W_hh = (const float*)d_in[2];
    const float* b_ih = (const float*)d_in[3];
    const float* b_hh = (const float*)d_in[4];
    const float* W_ya = (const float*)d_in[5];
    const float* b_ya = (const float*)d_in[6];
    const float* W_aa = (const float*)d_in[7];
    const float* b_aa = (const float*)d_in[8];
    float* out = (float*)d_out;

    char* ws = (char*)d_ws;
    const size_t MB = 1024 * 1024, KB = 1024;
    float*          xw    = (float*)(ws);                              // 64 MB
    unsigned short* Whh_b = (unsigned short*)(ws + 64 * MB);           // 512 KB
    unsigned short* Wya_b = (unsigned short*)(ws + 64 * MB + 512 * KB);
    unsigned short* Waa_b = (unsigned short*)(ws + 65 * MB);           // 512 KB
    unsigned short* hring = (unsigned short*)(ws + 65 * MB + 512 * KB);// 512 KB (8 slots)
    unsigned short* aring = (unsigned short*)(ws + 66 * MB);           // 128 KB (2 slots)
    int*            flg   = (int*)(ws + 66 * MB + 128 * KB);           // 1 KB (4x64 ints)

    conv_bf16<<<(H_ * H_) / 256, 256, 0, stream>>>(W_hh, W_ya, W_aa, Whh_b, Wya_b, Waa_b);

    // zero hring (512 KB) + aring (128 KB) contiguous = 163840 u32, then flags
    init_state<<<640, 256, 0, stream>>>((uint32_t*)hring, 163840);
    init_state<<<1,   256, 0, stream>>>((uint32_t*)flg, 256);

    dim3 gg(H_ / 64, (S_ * B_) / 64);
    xw_gemm<<<gg, 256, 0, stream>>>(x, W_ih, b_ih, b_hh, xw);

    scan_mfma<<<48, 256, 0, stream>>>(xw, Whh_b, Wya_b, Waa_b, b_ya, b_aa,
                                      hring, aring, flg, out);
}

// Round 9
// 3546.039 us; speedup vs baseline: 1.8930x; 1.4049x over previous
//
#include <hip/hip_runtime.h>
#include <cstdint>
#include <cstddef>

#define B_ 64
#define S_ 512
#define I_ 256
#define H_ 512
#define E_ 512

typedef __attribute__((ext_vector_type(8))) short bf16x8;
typedef __attribute__((ext_vector_type(4))) float f32x4;
typedef __attribute__((ext_vector_type(4))) unsigned int u32x4;
typedef __attribute__((ext_vector_type(2))) unsigned int u32x2;

__device__ __forceinline__ unsigned short f2b(float x) {
    uint32_t u = __builtin_bit_cast(uint32_t, x);
    uint32_t r = u + 0x7fffu + ((u >> 16) & 1u);
    return (unsigned short)(r >> 16);
}

// Compiler-only ordering for type-punned LDS repack (round-3 lesson:
// wide types don't TBAA-alias unsigned short; HW keeps DS ops in order).
__device__ __forceinline__ void lds_repack_fence() {
    __atomic_signal_fence(__ATOMIC_SEQ_CST);
    __builtin_amdgcn_wave_barrier();
}

// Compiler-only: keep relaxed data loads from being hoisted above the poll.
__device__ __forceinline__ void poll_fence() {
    __atomic_signal_fence(__ATOMIC_SEQ_CST);
}

// ---- batched coherent loads/stores (round-8 lesson) ----
// __hip_atomic_load lowers with a per-load wait: 32 coherent loads = 32
// serialized ~700cy IC round-trips = 9.2us/step measured. Inline asm issues
// all loads (sc0 sc1 = bypass L1+L2, served at the coherence point, same
// semantics as the relaxed-atomic lowering), then waits ONCE.
__device__ __forceinline__ u32x4 gl16(const void* p) {
    u32x4 d;
    asm volatile("global_load_dwordx4 %0, %1, off sc0 sc1"
                 : "=v"(d) : "v"((uint64_t)(uintptr_t)p));
    return d;
}
__device__ __forceinline__ void gs16(void* p, u32x4 v) {
    asm volatile("global_store_dwordx4 %0, %1, off sc0 sc1"
                 :: "v"((uint64_t)(uintptr_t)p), "v"(v) : "memory");
}
__device__ __forceinline__ void gs8(void* p, u32x2 v) {
    asm volatile("global_store_dwordx2 %0, %1, off sc0 sc1"
                 :: "v"((uint64_t)(uintptr_t)p), "v"(v) : "memory");
}
__device__ __forceinline__ void vm_wait0() {
    asm volatile("s_waitcnt vmcnt(0)" ::: "memory");
}
// Pin consumption of an asm-loaded value after a prior volatile asm wait
// (volatile asms execute in program order; this redefines v "after" the wait).
__device__ __forceinline__ void reg_tie(u32x4& v) {
    asm volatile("" : "+v"(v));
}

__device__ __forceinline__ int flag_ld(const int* p) {
    return __hip_atomic_load(p, __ATOMIC_RELAXED, __HIP_MEMORY_SCOPE_AGENT);
}
__device__ __forceinline__ void flag_st(int* p, int v) {
    __hip_atomic_store(p, v, __ATOMIC_RELAXED, __HIP_MEMORY_SCOPE_AGENT);
}

// ---- convert the three 512x512 recurrent matrices to bf16 (row-major) ----
__global__ __launch_bounds__(256) void conv_bf16(const float* __restrict__ whh,
                                                 const float* __restrict__ wya,
                                                 const float* __restrict__ waa,
                                                 unsigned short* __restrict__ owhh,
                                                 unsigned short* __restrict__ owya,
                                                 unsigned short* __restrict__ owaa) {
    int i = blockIdx.x * 256 + threadIdx.x;
    owhh[i] = f2b(whh[i]);
    owya[i] = f2b(wya[i]);
    owaa[i] = f2b(waa[i]);
}

__global__ __launch_bounds__(256) void init_state(uint32_t* __restrict__ p, int n) {
    int i = blockIdx.x * 256 + threadIdx.x;
    if (i < n) p[i] = 0u;
}

// ---------------- xw GEMM (fp32, unchanged — verified) ----------------
__global__ __launch_bounds__(256) void xw_gemm(const float* __restrict__ x,
                                               const float* __restrict__ W_ih,
                                               const float* __restrict__ b_ih,
                                               const float* __restrict__ b_hh,
                                               float* __restrict__ xw) {
    __shared__ float As[16][65];
    __shared__ float Bs[16][65];
    const int tid = threadIdx.x;
    const int m0 = blockIdx.y * 64;
    const int n0 = blockIdx.x * 64;

    const int lr = tid >> 2;
    const int lk = (tid & 3) * 4;

    const int m = m0 + lr;
    const float* xrow = x + ((size_t)(m & 63) * S_ + (m >> 6)) * I_;
    const float* brow = W_ih + (size_t)(n0 + lr) * I_;

    const int tm = (tid >> 4) * 4;
    const int tn = (tid & 15) * 4;

    float acc[4][4] = {{0.f}};

    for (int kt = 0; kt < I_; kt += 16) {
        float4 av = *(const float4*)(xrow + kt + lk);
        float4 bv = *(const float4*)(brow + kt + lk);
        As[lk + 0][lr] = av.x; As[lk + 1][lr] = av.y;
        As[lk + 2][lr] = av.z; As[lk + 3][lr] = av.w;
        Bs[lk + 0][lr] = bv.x; Bs[lk + 1][lr] = bv.y;
        Bs[lk + 2][lr] = bv.z; Bs[lk + 3][lr] = bv.w;
        __syncthreads();
#pragma unroll
        for (int k = 0; k < 16; ++k) {
            float a0 = As[k][tm + 0], a1 = As[k][tm + 1], a2 = As[k][tm + 2], a3 = As[k][tm + 3];
            float c0 = Bs[k][tn + 0], c1 = Bs[k][tn + 1], c2 = Bs[k][tn + 2], c3 = Bs[k][tn + 3];
            acc[0][0] += a0 * c0; acc[0][1] += a0 * c1; acc[0][2] += a0 * c2; acc[0][3] += a0 * c3;
            acc[1][0] += a1 * c0; acc[1][1] += a1 * c1; acc[1][2] += a1 * c2; acc[1][3] += a1 * c3;
            acc[2][0] += a2 * c0; acc[2][1] += a2 * c1; acc[2][2] += a2 * c2; acc[2][3] += a2 * c3;
            acc[3][0] += a3 * c0; acc[3][1] += a3 * c1; acc[3][2] += a3 * c2; acc[3][3] += a3 * c3;
        }
        __syncthreads();
    }

#pragma unroll
    for (int i = 0; i < 4; ++i) {
        int row = m0 + tm + i;
#pragma unroll
        for (int j = 0; j < 4; ++j) {
            int n = n0 + tn + j;
            xw[(size_t)row * H_ + n] = acc[i][j] + b_ih[n] + b_hh[n];
        }
    }
}

// ---------------- wave-autonomous MFMA scan, pipelined coherent state ----------------
// Structure identical to round 8 (release-free WG-aggregated signaling); the
// single change is batched inline-asm state loads/stores with ONE vmcnt wait.
// blocks 0..15  : h-WGs (4/group g=bid>>2). Wave w owns 32 h-cols.
// blocks 16..47 : a-WGs (8/group g=(bid-16)>>3). Wave w owns 16 a-cols.
// Publish: state stores (sc0 sc1) -> one vm_wait0 (acks at coherence point,
// no cache maintenance) -> lane0 ds_add on LDS counter; 4th wave stores the
// WG flag (relaxed). Flags: flg[g*64+0..3]=h-WGs, flg[g*64+4..11]=a-WGs.
// Poll: coalesced 12-word flag load + __ballot + s_sleep.
//   h-wave t: hflag>=t-1, aflag>=t-8 (h-ring depth-8 WAR).
//   a-wave t: hflag>=t, aflag>=t-1 (a-ring depth-2 WAR).
__global__ __launch_bounds__(256) void scan_mfma(const float* __restrict__ xw,
                                                 const unsigned short* __restrict__ Whh_b,
                                                 const unsigned short* __restrict__ Wya_b,
                                                 const unsigned short* __restrict__ Waa_b,
                                                 const float* __restrict__ b_ya,
                                                 const float* __restrict__ b_aa,
                                                 unsigned short* __restrict__ hring,  // 8*64*512 bf16
                                                 unsigned short* __restrict__ aring,  // 2*64*512 bf16
                                                 int* __restrict__ flg,               // 4 groups x 64 ints
                                                 float* __restrict__ out) {
    const int bid  = blockIdx.x;
    const int tid  = threadIdx.x;
    const int wave = tid >> 6;
    const int lane = tid & 63;
    const int l15  = lane & 15;
    const int quad = lane >> 4;

    __shared__ unsigned short wlds[4 * 2 * 16 * 64 * 8];  // 128 KB, per-wave partition
    __shared__ unsigned short pk[4][512];                  // per-wave repack staging
    __shared__ int sdone;                                  // monotone WG step counter

    if (tid == 0) sdone = 0;
    __syncthreads();   // once, before the loop

    uint64_t* hr64 = (uint64_t*)hring;
    uint64_t* ar64 = (uint64_t*)aring;

    if (bid < 16) {
        // ---------------- h-side ----------------
        const int g   = bid >> 2;
        const int b0  = g * 16;
        const int jw  = (bid & 3) * 128 + wave * 32;
        int*       fl_self = flg + g * 64 + (bid & 3);
        const int* fl_lane = flg + g * 64 + (lane < 12 ? lane : 0);
        const int  off = (lane < 4) ? 1 : (lane < 12 ? 8 : (1 << 30));

        // stage private Whh B-frags: B[k][j] = Whh[j][k], 16B/lane/frag
#pragma unroll
        for (int idx = 0; idx < 32; ++idx) {
            int s = idx >> 4, kb = idx & 15;
            const unsigned short* src = Whh_b + (size_t)(jw + s * 16 + l15) * H_ + kb * 32 + quad * 8;
            *(uint4*)&wlds[(((wave * 2 + s) * 16 + kb) * 64 + lane) * 8] = *(const uint4*)src;
        }
        lds_repack_fence();   // staging stores (uint4) vs loop reads (bf16x8): TBAA

        unsigned short* mypk = &pk[wave][0];
        const int prow = lane >> 2, pcg = lane & 3;

        for (int t = 1; t <= S_; ++t) {
            // xw prefetch: issued before the poll, consumed after MFMA
            float xwv[2][4];
#pragma unroll
            for (int s = 0; s < 2; ++s)
#pragma unroll
                for (int r = 0; r < 4; ++r)
                    xwv[s][r] = xw[((size_t)(t - 1) * B_ + b0 + quad * 4 + r) * H_ + jw + s * 16 + l15];

            for (;;) {   // merged poll: h_{t-1} ready + h-ring WAR guard
                int f = flag_ld(fl_lane);
                if (__ballot(f >= t - off) == ~0ull) break;
                __builtin_amdgcn_s_sleep(1);
            }
            poll_fence();

            // batched pipelined state load: 16x16B in flight, ONE wait
            const uint64_t* hsrc = hr64 + (size_t)((t - 1) & 7) * 8192 + (size_t)(b0 + l15) * 128 + quad * 2;
            u32x4 hv[16];
#pragma unroll
            for (int kb = 0; kb < 16; ++kb)
                hv[kb] = gl16((const char*)hsrc + (size_t)kb * 64);
            vm_wait0();
#pragma unroll
            for (int kb = 0; kb < 16; ++kb) reg_tie(hv[kb]);

            f32x4 a0 = {0.f, 0.f, 0.f, 0.f}, a1 = {0.f, 0.f, 0.f, 0.f};
#pragma unroll
            for (int kb = 0; kb < 16; ++kb) {
                bf16x8 hfv = __builtin_bit_cast(bf16x8, hv[kb]);
                bf16x8 b0f = *(const bf16x8*)&wlds[(((wave * 2 + 0) * 16 + kb) * 64 + lane) * 8];
                bf16x8 b1f = *(const bf16x8*)&wlds[(((wave * 2 + 1) * 16 + kb) * 64 + lane) * 8];
                a0 = __builtin_amdgcn_mfma_f32_16x16x32_bf16(hfv, b0f, a0, 0, 0, 0);
                a1 = __builtin_amdgcn_mfma_f32_16x16x32_bf16(hfv, b1f, a1, 0, 0, 0);
            }
            // tanh + C-layout -> row-major repack (16 rows x 32 cols)
#pragma unroll
            for (int r = 0; r < 4; ++r) {
                mypk[(quad * 4 + r) * 32 + 0  + l15] = f2b(tanhf(xwv[0][r] + a0[r]));
                mypk[(quad * 4 + r) * 32 + 16 + l15] = f2b(tanhf(xwv[1][r] + a1[r]));
            }
            lds_repack_fence();
            {
                const u32x4* pr4 = (const u32x4*)mypk;   // [16][4] 16B quanta
                u32x4 sv = pr4[prow * 4 + pcg];
                uint64_t* hdst = hr64 + (size_t)(t & 7) * 8192 + (size_t)(b0 + prow) * 128
                                 + (jw >> 2) + pcg * 2;
                gs16(hdst, sv);
            }
            vm_wait0();   // state acked at coherence point (no cache flush)
            poll_fence();
            if (lane == 0) {
                int old = __hip_atomic_fetch_add(&sdone, 1, __ATOMIC_RELAXED, __HIP_MEMORY_SCOPE_WORKGROUP);
                if (old == 4 * t - 1)
                    flag_st(fl_self, t);   // single relaxed WG flag store
            }
        }
    } else {
        // ---------------- a-side ----------------
        const int idx  = bid - 16;
        const int g    = idx >> 3;
        const int b0   = g * 16;
        const int jw   = (idx & 7) * 64 + wave * 16;
        int*       fl_self = flg + g * 64 + 4 + (idx & 7);
        const int* fl_lane = flg + g * 64 + (lane < 12 ? lane : 0);
        const int  off = (lane < 4) ? 0 : (lane < 12 ? 1 : (1 << 30));

        // stage private Wya (s=0) and Waa (s=1) B-frags
#pragma unroll
        for (int m = 0; m < 2; ++m)
#pragma unroll
            for (int kb = 0; kb < 16; ++kb) {
                const unsigned short* wb = m ? Waa_b : Wya_b;
                const unsigned short* src = wb + (size_t)(jw + l15) * H_ + kb * 32 + quad * 8;
                *(uint4*)&wlds[(((wave * 2 + m) * 16 + kb) * 64 + lane) * 8] = *(const uint4*)src;
            }
        lds_repack_fence();
        const float bias_a = b_ya[jw + l15] + b_aa[jw + l15];

        unsigned short* mypk = &pk[wave][0];
        const int prow = lane >> 2, pcg = lane & 3;

        for (int t = 1; t <= S_; ++t) {
            for (;;) {   // merged poll: h_t ready + a_{t-1} ready
                int f = flag_ld(fl_lane);
                if (__ballot(f >= t - off) == ~0ull) break;
                __builtin_amdgcn_s_sleep(1);
            }
            poll_fence();

            // h_t and a_{t-1}: 32x16B loads all in flight, ONE wait
            const uint64_t* hsrc = hr64 + (size_t)(t & 7) * 8192 + (size_t)(b0 + l15) * 128 + quad * 2;
            const uint64_t* asrc = ar64 + (size_t)((t - 1) & 1) * 8192 + (size_t)(b0 + l15) * 128 + quad * 2;
            u32x4 hv[16], av4[16];
#pragma unroll
            for (int kb = 0; kb < 16; ++kb) {
                hv[kb]  = gl16((const char*)hsrc + (size_t)kb * 64);
                av4[kb] = gl16((const char*)asrc + (size_t)kb * 64);
            }
            vm_wait0();
#pragma unroll
            for (int kb = 0; kb < 16; ++kb) { reg_tie(hv[kb]); reg_tie(av4[kb]); }

            f32x4 accy = {0.f, 0.f, 0.f, 0.f}, acca = {0.f, 0.f, 0.f, 0.f};
#pragma unroll
            for (int kb = 0; kb < 16; ++kb) {
                bf16x8 hfv = __builtin_bit_cast(bf16x8, hv[kb]);
                bf16x8 afv = __builtin_bit_cast(bf16x8, av4[kb]);
                bf16x8 by = *(const bf16x8*)&wlds[(((wave * 2 + 0) * 16 + kb) * 64 + lane) * 8];
                bf16x8 ba = *(const bf16x8*)&wlds[(((wave * 2 + 1) * 16 + kb) * 64 + lane) * 8];
                accy = __builtin_amdgcn_mfma_f32_16x16x32_bf16(hfv, by, accy, 0, 0, 0);
                acca = __builtin_amdgcn_mfma_f32_16x16x32_bf16(afv, ba, acca, 0, 0, 0);
            }
            float av[4];
#pragma unroll
            for (int r = 0; r < 4; ++r)
                av[r] = tanhf(accy[r] + acca[r] + bias_a);

            if (t < S_) {
#pragma unroll
                for (int r = 0; r < 4; ++r)
                    mypk[(quad * 4 + r) * 16 + l15] = f2b(av[r]);
                lds_repack_fence();
                u32x2 lv = ((const u32x2*)mypk)[prow * 4 + pcg];
                uint64_t* adst = ar64 + (size_t)(t & 1) * 8192 + (size_t)(b0 + prow) * 128
                                 + (jw >> 2) + pcg;
                gs8(adst, lv);
            } else {
#pragma unroll
                for (int r = 0; r < 4; ++r)
                    out[(size_t)(b0 + quad * 4 + r) * E_ + jw + l15] = av[r];
            }
            vm_wait0();
            poll_fence();
            if (lane == 0) {
                int old = __hip_atomic_fetch_add(&sdone, 1, __ATOMIC_RELAXED, __HIP_MEMORY_SCOPE_WORKGROUP);
                if (old == 4 * t - 1)
                    flag_st(fl_self, t);
            }
        }
    }
}

extern "C" void kernel_launch(void* const* d_in, const int* in_sizes, int n_in,
                              void* d_out, int out_size, void* d_ws, size_t ws_size,
                              hipStream_t stream) {
    const float* x    = (const float*)d_in[0];
    const float* W_ih = (const float*)d_in[1];
    const float* W_hh = (const float*)d_in[2];
    const float* b_ih = (const float*)d_in[3];
    const float* b_hh = (const float*)d_in[4];
    const float* W_ya = (const float*)d_in[5];
    const float* b_ya = (const float*)d_in[6];
    const float* W_aa = (const float*)d_in[7];
    const float* b_aa = (const float*)d_in[8];
    float* out = (float*)d_out;

    char* ws = (char*)d_ws;
    const size_t MB = 1024 * 1024, KB = 1024;
    float*          xw    = (float*)(ws);                              // 64 MB
    unsigned short* Whh_b = (unsigned short*)(ws + 64 * MB);           // 512 KB
    unsigned short* Wya_b = (unsigned short*)(ws + 64 * MB + 512 * KB);
    unsigned short* Waa_b = (unsigned short*)(ws + 65 * MB);           // 512 KB
    unsigned short* hring = (unsigned short*)(ws + 65 * MB + 512 * KB);// 512 KB (8 slots)
    unsigned short* aring = (unsigned short*)(ws + 66 * MB);           // 128 KB (2 slots)
    int*            flg   = (int*)(ws + 66 * MB + 128 * KB);           // 1 KB (4x64 ints)

    conv_bf16<<<(H_ * H_) / 256, 256, 0, stream>>>(W_hh, W_ya, W_aa, Whh_b, Wya_b, Waa_b);

    // zero hring (512 KB) + aring (128 KB) contiguous = 163840 u32, then flags
    init_state<<<640, 256, 0, stream>>>((uint32_t*)hring, 163840);
    init_state<<<1,   256, 0, stream>>>((uint32_t*)flg, 256);

    dim3 gg(H_ / 64, (S_ * B_) / 64);
    xw_gemm<<<gg, 256, 0, stream>>>(x, W_ih, b_ih, b_hh, xw);

    scan_mfma<<<48, 256, 0, stream>>>(xw, Whh_b, Wya_b, Waa_b, b_ya, b_aa,
                                      hring, aring, flg, out);
}